// Round 5
// baseline (292.523 us; speedup 1.0000x reference)
//
#include <hip/hip_runtime.h>

#define TT 128
#define BB 512
#define DD 500
#define NVOCAB 1000
#define NV4 125   // DD floats = 125 float4 per row (2000 B, 16B-aligned)

// ---------------------------------------------------------------------------
// Workspace layout (ws 16B-aligned), 140 KB total (desc dropped — it was
// measured neutral in rounds 2/4):
//   mask    : ulonglong2[BB]   (128-bit valid mask per column)        8 KB
//   lohi    : ushort[TT*BB]    (lo | hi<<7 per segment)             128 KB
//   ord     : int[BB]          (sorted column order)                  2 KB
//   slen    : int[BB]          (sorted lengths)                       2 KB
// ---------------------------------------------------------------------------

// Kernel 1: fused metadata + sort. ONE block, 512 threads (1 thread/column).
// Unchanged from round 4 (passed, ~10 us).
__global__ void __launch_bounds__(512)
meta_sort_kernel(const int* __restrict__ src,
                 const int* __restrict__ token_lengths,
                 const int* __restrict__ token_len_p,
                 unsigned short* __restrict__ lohi,
                 ulonglong2* __restrict__ mask,
                 int* __restrict__ ord,
                 int* __restrict__ slen,
                 float* __restrict__ out_len) {
    __shared__ int tl[NVOCAB];
    __shared__ int lens[BB];
    __shared__ int sord[BB];
    int b = threadIdx.x;
    for (int i = b; i < NVOCAB; i += 512) tl[i] = token_lengths[i];
    __syncthreads();

    // token_len arrives as a 1-element int array; guard vs f32 bits.
    int bits = token_len_p[0];
    int token_len = bits;
    if (bits > 1000000 || bits <= 0) token_len = (int)__int_as_float(bits);

    int curr = 0, seg = 0, lo = 0, pend = -1;
    unsigned long long m0 = 0ull, m1 = 0ull;
    for (int t0 = 0; t0 < TT; t0 += 16) {
        int s_arr[16];
        #pragma unroll
        for (int k = 0; k < 16; ++k) s_arr[k] = src[(t0 + k) * BB + b];
        #pragma unroll
        for (int k = 0; k < 16; ++k) {
            int t = t0 + k;
            int s = s_arr[k];
            if (s == 1) continue;              // pad: invalid
            int l = (s == 0) ? 4 : tl[s];
            if (pend >= 0 && curr + l > token_len) {
                lohi[seg * BB + b] = (unsigned short)(lo | (pend << 7));
                lo = pend + 1; curr = 0; seg++;
            }
            curr += l; pend = t;
            if (t < 64) m0 |= 1ull << t; else m1 |= 1ull << (t - 64);
        }
    }
    if (pend >= 0) {                           // final segment (nxt==BIG)
        lohi[seg * BB + b] = (unsigned short)(lo | (pend << 7));
        seg++;
    }
    mask[b] = make_ulonglong2(m0, m1);
    lens[b] = seg;
    __syncthreads();

    // stable descending rank-count sort (thread b doubles as output slot j)
    int lj = lens[b];
    int rank = 0;
    #pragma unroll 8
    for (int i = 0; i < BB; ++i) {
        int li = lens[i];
        rank += (int)((li > lj) || (li == lj && i < b));
    }
    sord[rank] = b;
    __syncthreads();
    int bb = sord[b];
    int n  = lens[bb];
    ord[b]  = bb;
    slen[b] = n;
    out_len[b] = (float)n;
}

// ---------------------------------------------------------------------------
// Kernel 2: gather. ONE WAVE OWNS 4 CONSECUTIVE OUTPUT ROWS (same r, columns
// j..j+3). All metadata is wave-uniform (-> SGPR loads), then 8 independent
// 1 KB emb loads (4 rows x {lane, lane+64}) are issued back-to-back and
// PINNED with __builtin_amdgcn_sched_barrier(0) — rounds 2/4 proved the
// compiler otherwise re-serializes to load->wait->use (VGPR stayed 32).
// Packed rows continue in lockstep s-steps: 8 pinned loads/step, clamped
// addresses + zero weight for rows whose segment already ended.
// Weights are exactly 0.0/1.0 so fmaf accumulation in ascending t is
// bit-exact vs the reference's sequential adds.
// ---------------------------------------------------------------------------
__device__ __forceinline__ float bitw(ulonglong2 m, int t) {
    unsigned long long w = (t < 64) ? m.x : m.y;
    return (float)((w >> (t & 63)) & 1ull);
}

__global__ void __launch_bounds__(256)
gather_kernel(const float* __restrict__ emb,
              const int* __restrict__ ord,
              const int* __restrict__ slen,
              const unsigned short* __restrict__ lohi,
              const ulonglong2* __restrict__ mask,
              float* __restrict__ out) {
    int wid  = threadIdx.x >> 6;
    int lane = threadIdx.x & 63;
    int base = (blockIdx.x * 4 + wid) * 4;       // 4 rows, same r (512%4==0)
    int r    = base >> 9;

    int q1   = lane + 64;
    bool has2 = q1 < NV4;                        // lanes 0..60
    int qc   = has2 ? q1 : (NV4 - 1);            // clamped: keeps loads uniform

    // ---- wave-uniform metadata (SGPR-path loads, all independent) ----
    int b[4], lo[4], hi[4], fo[4];
    ulonglong2 m[4];
    #pragma unroll
    for (int k = 0; k < 4; ++k) {
        int j  = (base + k) & (BB - 1);
        int bk = ord[j];
        int nk = slen[j];
        b[k] = bk;
        m[k] = mask[bk];
        if (r < nk) {
            int lh = (int)lohi[r * BB + bk];
            lo[k] = lh & 127; hi[k] = (lh >> 7) & 127; fo[k] = 0;
        } else {
            lo[k] = r; hi[k] = r; fo[k] = 1;     // identity row
        }
    }

    // ---- issue phase: 8 independent 1 KB loads, pinned ----
    float4 x0[4], x1[4];
    #pragma unroll
    for (int k = 0; k < 4; ++k) {
        const float4* row = (const float4*)(emb + ((size_t)lo[k] * BB + b[k]) * DD);
        x0[k] = row[lane];
        x1[k] = row[qc];
    }
    __builtin_amdgcn_sched_barrier(0);

    float4 a0[4], a1[4];
    #pragma unroll
    for (int k = 0; k < 4; ++k) {
        float w = fo[k] ? 1.0f : bitw(m[k], lo[k]);
        a0[k].x = w * x0[k].x; a0[k].y = w * x0[k].y;
        a0[k].z = w * x0[k].z; a0[k].w = w * x0[k].w;
        a1[k].x = w * x1[k].x; a1[k].y = w * x1[k].y;
        a1[k].z = w * x1[k].z; a1[k].w = w * x1[k].w;
    }

    // ---- lockstep continuation for packed rows ----
    int span01 = max(hi[0] - lo[0], hi[1] - lo[1]);
    int span23 = max(hi[2] - lo[2], hi[3] - lo[3]);
    int maxspan = max(span01, span23);           // 0 for all-identity waves

    for (int s = 1; s <= maxspan; ++s) {
        #pragma unroll
        for (int k = 0; k < 4; ++k) {
            int t = lo[k] + s;
            int tc = (t <= hi[k]) ? t : hi[k];   // clamp: valid addr, L2 hit
            const float4* row = (const float4*)(emb + ((size_t)tc * BB + b[k]) * DD);
            x0[k] = row[lane];
            x1[k] = row[qc];
        }
        __builtin_amdgcn_sched_barrier(0);
        #pragma unroll
        for (int k = 0; k < 4; ++k) {
            int t = lo[k] + s;
            float w = (t <= hi[k]) ? bitw(m[k], t) : 0.0f;  // fo rows: w=0 here
            a0[k].x = fmaf(w, x0[k].x, a0[k].x);
            a0[k].y = fmaf(w, x0[k].y, a0[k].y);
            a0[k].z = fmaf(w, x0[k].z, a0[k].z);
            a0[k].w = fmaf(w, x0[k].w, a0[k].w);
            a1[k].x = fmaf(w, x1[k].x, a1[k].x);
            a1[k].y = fmaf(w, x1[k].y, a1[k].y);
            a1[k].z = fmaf(w, x1[k].z, a1[k].z);
            a1[k].w = fmaf(w, x1[k].w, a1[k].w);
        }
    }

    // ---- stores: output rows are consecutive -> fully sequential writes ----
    #pragma unroll
    for (int k = 0; k < 4; ++k) {
        float4* orow = (float4*)(out + (size_t)(base + k) * DD);
        orow[lane] = a0[k];
        if (has2) orow[q1] = a1[k];
    }
}

extern "C" void kernel_launch(void* const* d_in, const int* in_sizes, int n_in,
                              void* d_out, int out_size, void* d_ws, size_t ws_size,
                              hipStream_t stream) {
    const float* embedded      = (const float*)d_in[0];
    const int*   src           = (const int*)d_in[1];
    // d_in[2] = lengths (unused by reference computation)
    const int*   token_lengths = (const int*)d_in[3];
    const int*   token_len_p   = (const int*)d_in[4];

    float* out = (float*)d_out;                 // T*B*D packed rows + B lengths

    ulonglong2*     mask = (ulonglong2*)d_ws;                       // 8 KB
    unsigned short* lohi = (unsigned short*)(mask + BB);            // 128 KB
    int*            ord  = (int*)(lohi + TT * BB);                  // 2 KB
    int*            slen = ord + BB;                                // 2 KB

    meta_sort_kernel<<<1, BB, 0, stream>>>(src, token_lengths, token_len_p,
                                           lohi, mask, ord, slen,
                                           out + (size_t)TT * BB * DD);
    // 4 waves/block x 4 rows/wave = 16 rows/block -> 4096 blocks
    gather_kernel<<<TT * BB / 16, 256, 0, stream>>>(embedded, ord, slen, lohi,
                                                    mask, out);
}

// Round 6
// 286.154 us; speedup vs baseline: 1.0223x; 1.0223x over previous
//
#include <hip/hip_runtime.h>

#define TT 128
#define BB 512
#define DD 500
#define NVOCAB 1000
#define NV4 125   // DD floats = 125 float4 per row (2000 B, 16B-aligned)

// ---------------------------------------------------------------------------
// Workspace layout (ws 16B-aligned), 140 KB:
//   mask    : ulonglong2[BB]   (128-bit valid mask per column)        8 KB
//   lohi    : ushort[TT*BB]    (lo | hi<<7 per segment)             128 KB
//   ord     : int[BB]          (sorted column order)                  2 KB
//   slen    : int[BB]          (sorted lengths)                       2 KB
// ---------------------------------------------------------------------------

// Kernel 1: fused metadata + sort. ONE block, 512 threads (1 thread/column).
// Unchanged from rounds 4/5 (passed both).
__global__ void __launch_bounds__(512)
meta_sort_kernel(const int* __restrict__ src,
                 const int* __restrict__ token_lengths,
                 const int* __restrict__ token_len_p,
                 unsigned short* __restrict__ lohi,
                 ulonglong2* __restrict__ mask,
                 int* __restrict__ ord,
                 int* __restrict__ slen,
                 float* __restrict__ out_len) {
    __shared__ int tl[NVOCAB];
    __shared__ int lens[BB];
    __shared__ int sord[BB];
    int b = threadIdx.x;
    for (int i = b; i < NVOCAB; i += 512) tl[i] = token_lengths[i];
    __syncthreads();

    // token_len arrives as a 1-element int array; guard vs f32 bits.
    int bits = token_len_p[0];
    int token_len = bits;
    if (bits > 1000000 || bits <= 0) token_len = (int)__int_as_float(bits);

    int curr = 0, seg = 0, lo = 0, pend = -1;
    unsigned long long m0 = 0ull, m1 = 0ull;
    for (int t0 = 0; t0 < TT; t0 += 16) {
        int s_arr[16];
        #pragma unroll
        for (int k = 0; k < 16; ++k) s_arr[k] = src[(t0 + k) * BB + b];
        #pragma unroll
        for (int k = 0; k < 16; ++k) {
            int t = t0 + k;
            int s = s_arr[k];
            if (s == 1) continue;              // pad: invalid
            int l = (s == 0) ? 4 : tl[s];
            if (pend >= 0 && curr + l > token_len) {
                lohi[seg * BB + b] = (unsigned short)(lo | (pend << 7));
                lo = pend + 1; curr = 0; seg++;
            }
            curr += l; pend = t;
            if (t < 64) m0 |= 1ull << t; else m1 |= 1ull << (t - 64);
        }
    }
    if (pend >= 0) {                           // final segment (nxt==BIG)
        lohi[seg * BB + b] = (unsigned short)(lo | (pend << 7));
        seg++;
    }
    mask[b] = make_ulonglong2(m0, m1);
    lens[b] = seg;
    __syncthreads();

    // stable descending rank-count sort (thread b doubles as output slot j)
    int lj = lens[b];
    int rank = 0;
    #pragma unroll 8
    for (int i = 0; i < BB; ++i) {
        int li = lens[i];
        rank += (int)((li > lj) || (li == lj && i < b));
    }
    sord[rank] = b;
    __syncthreads();
    int bb = sord[b];
    int n  = lens[bb];
    ord[b]  = bb;
    slen[b] = n;
    out_len[b] = (float)n;
}

// ---------------------------------------------------------------------------
// Kernel 2: gather — round-1 structure (best measured: 86.6 µs median) plus a
// ROW REMAP that runs identity rows FIRST. Mechanism: packed blocks previously
// sat at low blockIdx, so the HBM first-touch of the input was led by their
// scattered 2000 B column-hopping reads (1 MB stride) -> poor DRAM locality.
// Identity rows read source rows sequentially in r; processing r in the order
// (48, 49, ..., 127, 0, ..., 47) makes ~75% of the HBM fetch a clean
// streaming pass, and packed blocks (r < n <= ~44 by the segment-sum bound
// curr >= token_len-7) run last against a warm L3.
// Nothing in gather depends on processing order; every output row is written
// exactly once. FMA weights are exactly 0.0/1.0, ascending t => bit-exact.
// ---------------------------------------------------------------------------
__global__ void __launch_bounds__(256)
gather_kernel(const float* __restrict__ emb,
              const int* __restrict__ ord,
              const int* __restrict__ slen,
              const unsigned short* __restrict__ lohi,
              const ulonglong2* __restrict__ mask,
              float* __restrict__ out) {
    int lin  = blockIdx.x * 2 + (threadIdx.x >> 7);   // linear work item
    int lane = threadIdx.x & 127;
    int j  = lin & (BB - 1);
    int rl = lin >> 9;
    int r  = (rl + 48) & (TT - 1);                    // identity rows first
    int b = ord[j];
    int n = slen[j];
    if (lane >= NV4) return;

    float4* o = (float4*)(out + ((size_t)r * BB + j) * DD) + lane;

    if (r >= n) {
        // identity row: out[r][j] = emb[r][b]  (sequential-in-r read stream)
        *o = *((const float4*)(emb + ((size_t)r * BB + b) * DD) + lane);
    } else {
        int lh = (int)lohi[r * BB + b];
        int lo = lh & 127;
        int hi = (lh >> 7) & 127;
        ulonglong2 m = mask[b];
        float4 acc = make_float4(0.f, 0.f, 0.f, 0.f);
        for (int t = lo; t <= hi; ++t) {
            unsigned long long bit = (t < 64) ? (m.x >> t) : (m.y >> (t - 64));
            float w = (float)(bit & 1ull);
            float4 v = *((const float4*)(emb + ((size_t)t * BB + b) * DD) + lane);
            acc.x = fmaf(w, v.x, acc.x);
            acc.y = fmaf(w, v.y, acc.y);
            acc.z = fmaf(w, v.z, acc.z);
            acc.w = fmaf(w, v.w, acc.w);
        }
        *o = acc;
    }
}

extern "C" void kernel_launch(void* const* d_in, const int* in_sizes, int n_in,
                              void* d_out, int out_size, void* d_ws, size_t ws_size,
                              hipStream_t stream) {
    const float* embedded      = (const float*)d_in[0];
    const int*   src           = (const int*)d_in[1];
    // d_in[2] = lengths (unused by reference computation)
    const int*   token_lengths = (const int*)d_in[3];
    const int*   token_len_p   = (const int*)d_in[4];

    float* out = (float*)d_out;                 // T*B*D packed rows + B lengths

    ulonglong2*     mask = (ulonglong2*)d_ws;                       // 8 KB
    unsigned short* lohi = (unsigned short*)(mask + BB);            // 128 KB
    int*            ord  = (int*)(lohi + TT * BB);                  // 2 KB
    int*            slen = ord + BB;                                // 2 KB

    meta_sort_kernel<<<1, BB, 0, stream>>>(src, token_lengths, token_len_p,
                                           lohi, mask, ord, slen,
                                           out + (size_t)TT * BB * DD);
    gather_kernel<<<TT * BB / 2, 256, 0, stream>>>(embedded, ord, slen, lohi,
                                                   mask, out);
}